// Round 10
// baseline (3330.653 us; speedup 1.0000x reference)
//
#include <hip/hip_runtime.h>
#include <math.h>

// BiLSTM-CRF, round 10: r6 exchange (flags + bulk pull, proven 692us/lstm) with
// TWO independent batch-group chains software-pipelined per WG (32 WGs) so each
// chain's MALL round-trip hides behind the sibling chain's compute.
// B=64 S=256 V=50000 E=300 H=256 T=13
#define B_    64
#define S_    256
#define E_    300
#define H_    256
#define T_    13
#define G4_   1024   // 4*H
#define D2H_  512    // 2*H

typedef short bf16x8 __attribute__((ext_vector_type(8)));   // 8 bf16 in 4 VGPRs
typedef float f32x4  __attribute__((ext_vector_type(4)));
typedef unsigned short u16;
typedef unsigned long long u64;

__device__ __forceinline__ float sigf(float x)   { return __builtin_amdgcn_rcpf(1.f + __expf(-x)); }
__device__ __forceinline__ float tanhf_(float x) { return __builtin_amdgcn_rcpf(1.f + __expf(-2.f*x))*2.f - 1.f; }

__device__ __forceinline__ u16 f2bf(float f) {
  union { float f; unsigned u; } v; v.f = f;
  unsigned r = v.u + 0x7fff + ((v.u >> 16) & 1);   // RNE
  return (u16)(r >> 16);
}
__device__ __forceinline__ float bf2f(u16 h) {
  union { unsigned u; float f; } v; v.u = ((unsigned)h) << 16;
  return v.f;
}

// coherent (agent-scope, relaxed) accessors
__device__ __forceinline__ u64 cload64(const u64* p) {
  return __hip_atomic_load(p, __ATOMIC_RELAXED, __HIP_MEMORY_SCOPE_AGENT);
}
__device__ __forceinline__ void cstore32(unsigned* p, unsigned v) {
  __hip_atomic_store(p, v, __ATOMIC_RELAXED, __HIP_MEMORY_SCOPE_AGENT);
}

// ---------------- embedding gather -> bf16 hi/lo, K padded 300->320 ----------------
__global__ __launch_bounds__(64)
void k_embed(const int* __restrict__ x, const float* __restrict__ emb,
             u16* __restrict__ oh, u16* __restrict__ ol) {
  int bs = blockIdx.x;
  int xv = x[bs];
  const float4* src = (const float4*)(emb + (size_t)xv * E_);
  u64* dh = (u64*)(oh + (size_t)bs * 320);
  u64* dl = (u64*)(ol + (size_t)bs * 320);
  for (int q = threadIdx.x; q < 80; q += 64) {
    float4 v = (q < 75) ? src[q] : make_float4(0.f, 0.f, 0.f, 0.f);
    u16 hh[4], ll[4];
    float vv[4] = {v.x, v.y, v.z, v.w};
    #pragma unroll
    for (int j = 0; j < 4; j++) {
      hh[j] = f2bf(vv[j]);
      ll[j] = f2bf(vv[j] - bf2f(hh[j]));
    }
    dh[q] = (u64)hh[0] | ((u64)hh[1] << 16) | ((u64)hh[2] << 32) | ((u64)hh[3] << 48);
    dl[q] = (u64)ll[0] | ((u64)ll[1] << 16) | ((u64)ll[2] << 32) | ((u64)ll[3] << 48);
  }
}

// ---------------- fp32 -> bf16 hi/lo split (flat) ----------------
__global__ __launch_bounds__(256)
void k_cvtbf2(const float* __restrict__ w, u16* __restrict__ hi, u16* __restrict__ lo, int n) {
  int i = blockIdx.x * 256 + threadIdx.x;
  if (i < n) {
    float v = w[i];
    u16 h = f2bf(v);
    hi[i] = h;
    lo[i] = f2bf(v - bf2f(h));
  }
}

// ---------------- fp32 -> bf16 hi/lo with K padding (per-row) ----------------
__global__ __launch_bounds__(256)
void k_cvtpad(const float* __restrict__ w, u16* __restrict__ hi, u16* __restrict__ lo,
              int Ksrc, int Kpad) {
  int r = blockIdx.x;
  for (int k = threadIdx.x; k < Kpad; k += 256) {
    float v = (k < Ksrc) ? w[(size_t)r * Ksrc + k] : 0.f;
    u16 h = f2bf(v);
    hi[(size_t)r * Kpad + k] = h;
    lo[(size_t)r * Kpad + k] = f2bf(v - bf2f(h));
  }
}

// ---------------- cond_w (512,256) -> transposed hi/lo (256,512) ----------------
__global__ __launch_bounds__(256)
void k_cvtT(const float* __restrict__ w, u16* __restrict__ hi, u16* __restrict__ lo) {
  int n = blockIdx.x;
  for (int k = threadIdx.x; k < 512; k += 256) {
    float v = w[(size_t)k * 256 + n];
    u16 h = f2bf(v);
    hi[(size_t)n * 512 + k] = h;
    lo[(size_t)n * 512 + k] = f2bf(v - bf2f(h));
  }
}

// ---------------- split-bf16 MFMA GEMM: C = A @ W^T + bias (round-6) ----------------
__global__ __launch_bounds__(256)
void k_bgemm(const u16* __restrict__ Ahi, const u16* __restrict__ Alo,
             const u16* __restrict__ Whi, const u16* __restrict__ Wlo,
             const float* __restrict__ bias, float* __restrict__ C,
             int K, int N, int permute, long wStride, long bStride, long cStride)
{
  __shared__ u16 Ash[2][128 * 40];
  __shared__ u16 Wsh[2][128 * 40];

  int tid = threadIdx.x;
  int d   = blockIdx.z;
  int n0  = blockIdx.x * 128, m0 = blockIdx.y * 128;
  int lane = tid & 63;
  int w    = tid >> 6;
  int l15  = lane & 15;
  int quad = lane >> 4;
  int mh = (w >> 1) * 64, nh = (w & 1) * 64;

  int comp = tid >> 7, row = tid & 127;
  int gr = m0 + row;
  int ar = permute ? ((gr & 63) * S_ + (gr >> 6)) : gr;
  const u16* Asrc = (comp ? Alo : Ahi) + (size_t)ar * K;
  const u16* Wsrc = (comp ? Wlo : Whi) + (size_t)d * wStride + (size_t)(n0 + row) * K;
  u16* AshC = &Ash[comp][row * 40];
  u16* WshC = &Wsh[comp][row * 40];

  f32x4 acc[4][4];
  #pragma unroll
  for (int mt = 0; mt < 4; mt++)
    #pragma unroll
    for (int nt = 0; nt < 4; nt++) acc[mt][nt] = (f32x4)(0.f);

  for (int k0 = 0; k0 < K; k0 += 32) {
    float4 a0 = *(const float4*)(Asrc + k0);
    float4 a1 = *(const float4*)(Asrc + k0 + 8);
    float4 a2 = *(const float4*)(Asrc + k0 + 16);
    float4 a3 = *(const float4*)(Asrc + k0 + 24);
    float4 w0 = *(const float4*)(Wsrc + k0);
    float4 w1 = *(const float4*)(Wsrc + k0 + 8);
    float4 w2 = *(const float4*)(Wsrc + k0 + 16);
    float4 w3 = *(const float4*)(Wsrc + k0 + 24);
    __syncthreads();
    *(float4*)(AshC)      = a0; *(float4*)(AshC + 8)  = a1;
    *(float4*)(AshC + 16) = a2; *(float4*)(AshC + 24) = a3;
    *(float4*)(WshC)      = w0; *(float4*)(WshC + 8)  = w1;
    *(float4*)(WshC + 16) = w2; *(float4*)(WshC + 24) = w3;
    __syncthreads();

    bf16x8 ah[4], al[4], bh[4], bl[4];
    #pragma unroll
    for (int mt = 0; mt < 4; mt++) {
      int rr = mh + mt * 16 + l15;
      ah[mt] = *(const bf16x8*)&Ash[0][rr * 40 + quad * 8];
      al[mt] = *(const bf16x8*)&Ash[1][rr * 40 + quad * 8];
    }
    #pragma unroll
    for (int nt = 0; nt < 4; nt++) {
      int rr = nh + nt * 16 + l15;
      bh[nt] = *(const bf16x8*)&Wsh[0][rr * 40 + quad * 8];
      bl[nt] = *(const bf16x8*)&Wsh[1][rr * 40 + quad * 8];
    }
    #pragma unroll
    for (int mt = 0; mt < 4; mt++)
      #pragma unroll
      for (int nt = 0; nt < 4; nt++) {
        acc[mt][nt] = __builtin_amdgcn_mfma_f32_16x16x32_bf16(ah[mt], bh[nt], acc[mt][nt], 0, 0, 0);
        acc[mt][nt] = __builtin_amdgcn_mfma_f32_16x16x32_bf16(ah[mt], bl[nt], acc[mt][nt], 0, 0, 0);
        acc[mt][nt] = __builtin_amdgcn_mfma_f32_16x16x32_bf16(al[mt], bh[nt], acc[mt][nt], 0, 0, 0);
      }
  }

  const float* biasd = bias + (size_t)d * bStride;
  float* Cd = C + (size_t)d * cStride;
  #pragma unroll
  for (int nt = 0; nt < 4; nt++) {
    int cn = n0 + nh + nt * 16 + l15;
    float bv = biasd[cn];
    #pragma unroll
    for (int mt = 0; mt < 4; mt++) {
      int mr = m0 + mh + mt * 16 + quad * 4;
      #pragma unroll
      for (int j = 0; j < 4; j++)
        Cd[(size_t)(mr + j) * N + cn] = acc[mt][nt][j] + bv;
    }
  }
}

// ---------------- split-bf16 MFMA LSTM, 2-chain pipelined, r6 exchange ----------------
// 32 WGs: blockIdx.x = d*16 + bp*8 + us. Each WG runs chains bg = bp*2, bp*2+1
// (independent recurrences, same Whh A-frags). Per chain the exchange is exactly
// round-6: coherent u32 hi/lo stores to per-step buffers, drain barrier, magic
// flag; consumer spins 8 flags then bulk-pulls 16 KB once. Chain B's compute
// hides chain A's MALL round-trip and vice versa.
__global__ __launch_bounds__(256, 1)
void k_lstm_mfma(const float* __restrict__ xg,
                 const u16* __restrict__ Whi, const u16* __restrict__ Wlo,
                 u16* __restrict__ houth, u16* __restrict__ houtl,
                 u16* __restrict__ hb_hi, u16* __restrict__ hb_lo,
                 unsigned* __restrict__ flags, unsigned magic)
{
  __shared__ __align__(16) u16   hsh[16 * 256];        // 8 KB hi slab (shared by chains)
  __shared__ __align__(16) u16   hsl[16 * 256];        // 8 KB lo slab
  __shared__ __align__(16) float gl[4 * 16 * 34];      // gates [g][b][u32 pad34]

  int tid  = threadIdx.x;
  int us   = blockIdx.x & 7;
  int bp   = (blockIdx.x >> 3) & 1;
  int d    = blockIdx.x >> 4;
  int lane = tid & 63;
  int gate = tid >> 6;
  int l15  = lane & 15;
  int quad = lane >> 4;

  // shared A-frags (same d, us for both chains)
  bf16x8 afh[2][8], afl[2][8];
  {
    const u16* WbH = Whi + ((size_t)d * G4_ + gate * 256 + us * 32 + l15) * H_;
    const u16* WbL = Wlo + ((size_t)d * G4_ + gate * 256 + us * 32 + l15) * H_;
    #pragma unroll
    for (int mt = 0; mt < 2; mt++)
      #pragma unroll
      for (int kt = 0; kt < 8; kt++) {
        afh[mt][kt] = *(const bf16x8*)(WbH + (size_t)mt * 16 * H_ + kt * 32 + quad * 8);
        afl[mt][kt] = *(const bf16x8*)(WbL + (size_t)mt * 16 * H_ + kt * 32 + quad * 8);
      }
  }

  float c0s[2] = {0.f, 0.f}, c1s[2] = {0.f, 0.f};
  int sb = tid >> 4, cg = tid & 15;          // staging: batch row, chunk-pair group
  int bc = tid & 15, uo2 = (tid >> 4) * 2;   // cell: batch, unit pair

  const float* xgd = xg + (size_t)d * S_ * B_ * G4_;
  u16*      hbh_c[2]; u16* hbl_c[2]; unsigned* fl_c[2]; int bgs[2];
  #pragma unroll
  for (int ch = 0; ch < 2; ch++) {
    int bg = bp * 2 + ch;
    bgs[ch] = bg;
    size_t isl = (size_t)(d * 4 + bg) * S_ * 16 * 256;
    hbh_c[ch] = hb_hi + isl;
    hbl_c[ch] = hb_lo + isl;
    fl_c[ch]  = flags + (d * 4 + bg) * S_ * 8;
  }

  for (int it = 0; it < S_; it++) {
    int s = d ? (S_ - 1 - it) : it;

    #pragma unroll
    for (int ch = 0; ch < 2; ch++) {
      int bg = bgs[ch];
      u16* hbh = hbh_c[ch];
      u16* hbl = hbl_c[ch];
      unsigned* fl = fl_c[ch];

      // acc init from xg (issued before the spin; flies during the wait)
      f32x4 acc[2];
      const float* xgrow = xgd + (size_t)s * B_ * G4_ + (size_t)(bg * 16 + l15) * G4_
                         + gate * 256 + us * 32;
      acc[0] = *(const f32x4*)(xgrow + quad * 4);
      acc[1] = *(const f32x4*)(xgrow + 16 + quad * 4);

      if (it > 0) {
        // wait for all 8 slices of this chain's previous step
        if (tid < 8) {
          const unsigned* f = &fl[(it - 1) * 8 + tid];
          while (__hip_atomic_load(f, __ATOMIC_RELAXED, __HIP_MEMORY_SCOPE_AGENT) != magic)
            __builtin_amdgcn_s_sleep(1);
        }
        __syncthreads();

        // bulk pull 16KB slab (hi+lo) -> LDS, XOR chunk swizzle (r6 mapping)
        {
          const u64* gh = (const u64*)(hbh + (size_t)(it - 1) * 4096 + sb * 256) + cg * 4;
          const u64* gq = (const u64*)(hbl + (size_t)(it - 1) * 4096 + sb * 256) + cg * 4;
          u64 th[4], tl[4];
          #pragma unroll
          for (int q = 0; q < 4; q++) { th[q] = cload64(gh + q); tl[q] = cload64(gq + q); }
          #pragma unroll
          for (int q = 0; q < 4; q++) {
            int chk = cg * 2 + (q >> 1);
            int cc = chk ^ sb;
            ((u64*)&hsh[sb * 256 + cc * 8])[q & 1] = th[q];
            ((u64*)&hsl[sb * 256 + cc * 8])[q & 1] = tl[q];
          }
        }
        __syncthreads();

        #pragma unroll
        for (int kt = 0; kt < 8; kt++) {
          int cc = (kt * 4 + quad) ^ l15;
          bf16x8 bh = *(const bf16x8*)&hsh[l15 * 256 + cc * 8];
          bf16x8 bl = *(const bf16x8*)&hsl[l15 * 256 + cc * 8];
          #pragma unroll
          for (int mt = 0; mt < 2; mt++) {
            acc[mt] = __builtin_amdgcn_mfma_f32_16x16x32_bf16(afh[mt][kt], bh, acc[mt], 0, 0, 0);
            acc[mt] = __builtin_amdgcn_mfma_f32_16x16x32_bf16(afh[mt][kt], bl, acc[mt], 0, 0, 0);
            acc[mt] = __builtin_amdgcn_mfma_f32_16x16x32_bf16(afl[mt][kt], bh, acc[mt], 0, 0, 0);
          }
        }
      }

      // publish gates: u_local = mt*16 + quad*4 + r, batch = l15
      #pragma unroll
      for (int mt = 0; mt < 2; mt++)
        *(f32x4*)&gl[(gate * 16 + l15) * 34 + mt * 16 + quad * 4] = acc[mt];
      __syncthreads();

      // cell update: thread owns (bc, units uo2, uo2+1)
      float2 vi = *(const float2*)&gl[(0 * 16 + bc) * 34 + uo2];
      float2 vf = *(const float2*)&gl[(1 * 16 + bc) * 34 + uo2];
      float2 vg = *(const float2*)&gl[(2 * 16 + bc) * 34 + uo2];
      float2 vo = *(const float2*)&gl[(3 * 16 + bc) * 34 + uo2];
      float c0 = sigf(vf.x) * c0s[ch] + sigf(vi.x) * tanhf_(vg.x);
      float c1 = sigf(vf.y) * c1s[ch] + sigf(vi.y) * tanhf_(vg.y);
      c0s[ch] = c0; c1s[ch] = c1;
      float h0 = sigf(vo.x) * tanhf_(c0);
      float h1 = sigf(vo.y) * tanhf_(c1);

      u16 h0h = f2bf(h0), h1h = f2bf(h1);
      u16 h0l = f2bf(h0 - bf2f(h0h)), h1l = f2bf(h1 - bf2f(h1h));
      unsigned phv = (unsigned)h0h | ((unsigned)h1h << 16);
      unsigned plv = (unsigned)h0l | ((unsigned)h1l << 16);

      // h -> layer output (bf16 hi/lo, plain stores)
      size_t ho = ((size_t)(bg * 16 + bc) * S_ + s) * D2H_ + d * H_ + us * 32 + uo2;
      *(unsigned*)(houth + ho) = phv;
      *(unsigned*)(houtl + ho) = plv;

      // h -> exchange buffers (agent-coherent)
      size_t hoff = (size_t)it * 4096 + bc * 256 + us * 32 + uo2;
      cstore32((unsigned*)(hbh + hoff), phv);
      cstore32((unsigned*)(hbl + hoff), plv);

      __syncthreads();   // drains this chain's coherent stores + protects gl/hs reuse
      if (tid == 0)
        __hip_atomic_store(&fl[it * 8 + us], magic, __ATOMIC_RELAXED, __HIP_MEMORY_SCOPE_AGENT);
      // chain B's phase now runs while chain A's stores/flag propagate through MALL
    }
  }
}

// ---------------- block reduction helpers ----------------
__device__ __forceinline__ float bsum(float v, float* sb) {
  int t = threadIdx.x;
  sb[t] = v; __syncthreads();
  for (int s = 128; s; s >>= 1) { if (t < s) sb[t] += sb[t + s]; __syncthreads(); }
  float r = sb[0]; __syncthreads(); return r;
}
__device__ __forceinline__ float bmax(float v, float* sb) {
  int t = threadIdx.x;
  sb[t] = v; __syncthreads();
  for (int s = 128; s; s >>= 1) { if (t < s) sb[t] = fmaxf(sb[t], sb[t + s]); __syncthreads(); }
  float r = sb[0]; __syncthreads(); return r;
}

// ---------------- pos branch ----------------
__global__ __launch_bounds__(256)
void k_pos(const float* __restrict__ pos, const float* __restrict__ fc1w, const float* __restrict__ fc1b,
           const float* __restrict__ fc2w, const float* __restrict__ fc2b,
           const float* __restrict__ lng, const float* __restrict__ lnb, float* __restrict__ pos_out)
{
  __shared__ float sp[256], sh[256], sb[256];
  int b = blockIdx.x, t = threadIdx.x;
  sp[t] = pos[b * 256 + t];
  __syncthreads();
  float a1 = fc1b[t];
  for (int s = 0; s < 256; s++) a1 += sp[s] * fc1w[s * 256 + t];
  a1 = fmaxf(a1, 0.f);
  sh[t] = a1; __syncthreads();
  float a2 = fc2b[t] + sp[t];
  for (int s = 0; s < 256; s++) a2 += sh[s] * fc2w[s * 256 + t];
  float m   = bsum(a2, sb) * (1.f / 256.f);
  float cen = a2 - m;
  float var = bsum(cen * cen, sb) * (1.f / 256.f);
  pos_out[b * 256 + t] = cen * rsqrtf(var + 1e-5f) * lng[t] + lnb[t];
}

// ---------------- CLN stage A ----------------
__global__ __launch_bounds__(256)
void k_clnA(const float* __restrict__ pos_out, const float* __restrict__ wd, const float* __restrict__ bd,
            const float* __restrict__ cw, const float* __restrict__ cb,
            float* __restrict__ wvec, float* __restrict__ bbvec)
{
  __shared__ float sp[256];
  int b = blockIdx.x, t = threadIdx.x;
  sp[t] = pos_out[b * 256 + t];
  __syncthreads();
  const float4* wdr = (const float4*)(wd + (size_t)t * 256);
  const float4* bdr = (const float4*)(bd + (size_t)t * 256);
  float aw = 0.f, ab = 0.f;
  for (int q = 0; q < 64; q++) {
    float4 w4 = wdr[q], b4 = bdr[q];
    float s0 = sp[q*4], s1 = sp[q*4+1], s2 = sp[q*4+2], s3 = sp[q*4+3];
    aw += s0*w4.x + s1*w4.y + s2*w4.z + s3*w4.w;
    ab += s0*b4.x + s1*b4.y + s2*b4.z + s3*b4.w;
  }
  wvec [b * 256 + t] = aw + cw[t];
  bbvec[b * 256 + t] = ab + cb[t];
}

// ---------------- CLN stage B + sentence dot ----------------
__global__ __launch_bounds__(256)
void k_clnB(const float* __restrict__ oc, const float* __restrict__ wvec, const float* __restrict__ bbvec,
            const float* __restrict__ alw, const float* __restrict__ alb,
            float* __restrict__ outn, float* __restrict__ sentence)
{
  __shared__ float sb[256];
  int bs = blockIdx.x, t = threadIdx.x;
  int b = bs >> 8;
  float v   = oc[(size_t)bs * 256 + t];
  float m   = bsum(v, sb) * (1.f / 256.f);
  float cen = v - m;
  float var = bsum(cen * cen, sb) * (1.f / 256.f);
  float o   = cen * rsqrtf(var + 1e-12f) * wvec[b * 256 + t] + bbvec[b * 256 + t];
  outn[(size_t)bs * 256 + t] = o;
  float sv = bsum(o * alw[t], sb);
  if (t == 0) sentence[bs] = sv + alb[0];
}

// ---------------- attention ----------------
__global__ __launch_bounds__(256)
void k_att(const float* __restrict__ sentence,
           const float* __restrict__ wq, const float* __restrict__ bq,
           const float* __restrict__ wk, const float* __restrict__ bk,
           const float* __restrict__ wv, const float* __restrict__ bv,
           const float* __restrict__ lng, const float* __restrict__ lnb,
           float* __restrict__ att)
{
  __shared__ float ss[256], sb[256];
  int b = blockIdx.x, t = threadIdx.x;
  ss[t] = sentence[b * 256 + t];
  __syncthreads();
  float q = bq[t], k = bk[t], vv = bv[t];
  for (int s = 0; s < 256; s++) {
    float sv = ss[s];
    q  += sv * wq[s * 256 + t];
    k  += sv * wk[s * 256 + t];
    vv += sv * wv[s * 256 + t];
  }
  float x  = q * k * (1.f / 16.f);
  float mx = bmax(x, sb);
  float e  = expf(x - mx);
  float sm = bsum(e, sb);
  float a  = (e / sm) * vv;
  float m   = bsum(a, sb) * (1.f / 256.f);
  float cen = a - m;
  float var = bsum(cen * cen, sb) * (1.f / 256.f);
  att[b * 256 + t] = cen * rsqrtf(var + 1e-5f) * lng[t] + lnb[t];
}

// ---------------- logits ----------------
__global__ __launch_bounds__(64)
void k_out(const float* __restrict__ outn, const float* __restrict__ att,
           const float* __restrict__ ow, const float* __restrict__ ob,
           float* __restrict__ logits)
{
  __shared__ float row[256];
  int bs = blockIdx.x, t = threadIdx.x;
  ((float4*)row)[t] = ((const float4*)(outn + (size_t)bs * 256))[t];
  __syncthreads();
  float a = att[bs];
  if (t < T_) {
    float acc = 0.f;
    for (int c = 0; c < 256; c++) acc += row[c] * ow[c * T_ + t];
    logits[(size_t)bs * T_ + t] = a * acc + ob[t];
  }
}

// ---------------- Viterbi ----------------
__global__ __launch_bounds__(64)
void k_viterbi(const float* __restrict__ logits, const float* __restrict__ start,
               const float* __restrict__ endv, const float* __restrict__ trans,
               float* __restrict__ tags)
{
  __shared__ float sc[16];
  __shared__ float str[169];
  __shared__ unsigned char hist[255 * 13];
  __shared__ int tg[256];
  int b = blockIdx.x, t = threadIdx.x;
  for (int i = t; i < 169; i += 64) str[i] = trans[i];
  if (t < 13) sc[t] = start[t] + logits[((size_t)b * 256) * 13 + t];
  __syncthreads();
  for (int s = 1; s < 256; s++) {
    float best = -1e30f; int bi = 0;
    if (t < 13) {
      best = sc[0] + str[t]; bi = 0;
      for (int i = 1; i < 13; i++) {
        float v = sc[i] + str[i * 13 + t];
        if (v > best) { best = v; bi = i; }
      }
    }
    __syncthreads();
    if (t < 13) {
      sc[t] = best + logits[((size_t)b * 256 + s) * 13 + t];
      hist[(s - 1) * 13 + t] = (unsigned char)bi;
    }
    __syncthreads();
  }
  if (t == 0) {
    float best = sc[0] + endv[0]; int last = 0;
    for (int j = 1; j < 13; j++) {
      float v = sc[j] + endv[j];
      if (v > best) { best = v; last = j; }
    }
    tg[255] = last;
    int cur = last;
    for (int s = 254; s >= 0; s--) { cur = hist[s * 13 + cur]; tg[s] = cur; }
  }
  __syncthreads();
  for (int s = t; s < 256; s += 64) tags[b * 256 + s] = (float)tg[s];
}

// ---------------- launch ----------------
extern "C" void kernel_launch(void* const* d_in, const int* in_sizes, int n_in,
                              void* d_out, int out_size, void* d_ws, size_t ws_size,
                              hipStream_t stream)
{
  const int*   x     = (const int*)  d_in[0];
  const float* pos   = (const float*)d_in[1];
  const float* emb   = (const float*)d_in[2];
  const float* Wih0  = (const float*)d_in[3];
  const float* Whh0  = (const float*)d_in[4];
  const float* b0    = (const float*)d_in[5];
  const float* Wih1  = (const float*)d_in[6];
  const float* Whh1  = (const float*)d_in[7];
  const float* b1    = (const float*)d_in[8];
  const float* fc1w  = (const float*)d_in[9];
  const float* fc1b  = (const float*)d_in[10];
  const float* fc2w  = (const float*)d_in[11];
  const float* fc2b  = (const float*)d_in[12];
  const float* plng  = (const float*)d_in[13];
  const float* plnb  = (const float*)d_in[14];
  const float* condw = (const float*)d_in[15];
  const float* condb = (const float*)d_in[16];
  const float* clnw  = (const float*)d_in[17];
  const float* clnb  = (const float*)d_in[18];
  const float* clnwd = (const float*)d_in[19];
  const float* clnbd = (const float*)d_in[20];
  const float* wq    = (const float*)d_in[21];
  const float* bq    = (const float*)d_in[22];
  const float* wk    = (const float*)d_in[23];
  const float* bk    = (const float*)d_in[24];
  const float* wv    = (const float*)d_in[25];
  const float* bv    = (const float*)d_in[26];
  const float* atlng = (const float*)d_in[27];
  const float* atlnb = (const float*)d_in[28];
  const float* alw   = (const float*)d_in[29];
  const float* alb   = (const float*)d_in[30];
  const float* ow    = (const float*)d_in[31];
  const float* ob    = (const float*)d_in[32];
  const float* cstart= (const float*)d_in[33];
  const float* cend  = (const float*)d_in[34];
  const float* ctrans= (const float*)d_in[35];

  const size_t BS = (size_t)B_ * S_;   // 16384
  float* ws = (float*)d_ws;
  float* r1   = ws;                    // embA hi/lo -> out_cond
  float* xg   = r1 + 5242880;          // fp32 pre-gates [2][S][B][1024]
  float* l0r  = xg + 33554432;         // l0 hi/lo -> lstm1 exchange -> outn
  float* l1r  = l0r + 8388608;         // lstm0 exchange -> l1 hi/lo
  float* pos_out  = l1r + 8388608;
  float* wvec     = pos_out + 16384;
  float* bbvec    = wvec + 16384;
  float* sentence = bbvec + 16384;
  float* attv     = sentence + 16384;
  unsigned* flags = (unsigned*)(attv + 16384);     // 2*4*256*8 = 16384 u32
  u16* whhh0 = (u16*)(flags + 16384);              // Whh splits: 4 x 524288 u16
  u16* whhl0 = whhh0 + 524288;
  u16* whhh1 = whhl0 + 524288;
  u16* whhl1 = whhh1 + 524288;
  u16* wih0h = whhl1 + 524288;                     // [2][1024][320]
  u16* wih0l = wih0h + 655360;
  u16* wih1h = wih0l + 655360;                     // [2][1024][512]
  u16* wih1l = wih1h + 1048576;
  u16* condTh = wih1l + 1048576;                   // [256][512]
  u16* condTl = condTh + 131072;

  u16* embh = (u16*)r1;
  u16* embl = embh + 5242880;
  float* out_cond = r1;
  u16* l0h = (u16*)l0r;
  u16* l0l = l0h + 8388608;
  u16* l1h = (u16*)l1r;
  u16* l1l = l1h + 8388608;
  const size_t HBN = (size_t)8 * S_ * 16 * 256;    // 8,388,608 u16 per component
  u16* hb0 = (u16*)l1r;                 // lstm0 exchange (l1r free until lstm1 hout)
  u16* hb1 = (u16*)l0r;                 // lstm1 exchange (l0 consumed by bgemm1)
  float* outn = l0r;
  float* logits = (float*)d_out;
  float* tags   = logits + BS * T_;

  k_embed <<<dim3(B_ * S_), dim3(64), 0, stream>>>(x, emb, embh, embl);
  k_cvtbf2<<<dim3(2048), dim3(256), 0, stream>>>(Whh0, whhh0, whhl0, 2 * G4_ * H_);
  k_cvtbf2<<<dim3(2048), dim3(256), 0, stream>>>(Whh1, whhh1, whhl1, 2 * G4_ * H_);
  k_cvtpad<<<dim3(2048), dim3(256), 0, stream>>>(Wih0, wih0h, wih0l, 300, 320);
  k_cvtpad<<<dim3(2048), dim3(256), 0, stream>>>(Wih1, wih1h, wih1l, 512, 512);
  k_cvtT  <<<dim3(256),  dim3(256), 0, stream>>>(condw, condTh, condTl);

  // layer-0 pre-gates (split-bf16 MFMA)
  k_bgemm<<<dim3(8, 128, 2), dim3(256), 0, stream>>>(
      embh, embl, wih0h, wih0l, b0, xg, 320, G4_, 1,
      (long)G4_ * 320, (long)G4_, (long)BS * G4_);
  k_lstm_mfma<<<dim3(32), dim3(256), 0, stream>>>(
      xg, whhh0, whhl0, l0h, l0l, hb0, hb0 + HBN, flags, 0x51A75A01u);

  // layer-1 pre-gates
  k_bgemm<<<dim3(8, 128, 2), dim3(256), 0, stream>>>(
      l0h, l0l, wih1h, wih1l, b1, xg, 512, G4_, 1,
      (long)G4_ * 512, (long)G4_, (long)BS * G4_);
  k_lstm_mfma<<<dim3(32), dim3(256), 0, stream>>>(
      xg, whhh1, whhl1, l1h, l1l, hb1, hb1 + HBN, flags, 0x51A75A02u);

  // cond projection
  k_bgemm<<<dim3(2, 128, 1), dim3(256), 0, stream>>>(
      l1h, l1l, condTh, condTl, condb, out_cond, 512, 256, 0, 0, 0, 0);

  k_pos <<<dim3(B_), dim3(256), 0, stream>>>(pos, fc1w, fc1b, fc2w, fc2b, plng, plnb, pos_out);
  k_clnA<<<dim3(B_), dim3(256), 0, stream>>>(pos_out, clnwd, clnbd, clnw, clnb, wvec, bbvec);
  k_clnB<<<dim3(B_ * S_), dim3(256), 0, stream>>>(out_cond, wvec, bbvec, alw, alb, outn, sentence);
  k_att <<<dim3(B_), dim3(256), 0, stream>>>(sentence, wq, bq, wk, bk, wv, bv, atlng, atlnb, attv);
  k_out <<<dim3(B_ * S_), dim3(64), 0, stream>>>(outn, attv, ow, ob, logits);
  k_viterbi<<<dim3(B_), dim3(64), 0, stream>>>(logits, cstart, cend, ctrans, tags);
}

// Round 11
// 1677.388 us; speedup vs baseline: 1.9856x; 1.9856x over previous
//
#include <hip/hip_runtime.h>
#include <math.h>

// BiLSTM-CRF, round 11: r6 exchange discipline (flags + single bulk pull) with
// islands shrunk 16->4 batches (256 WGs, 1/CU). Per-step pull 16KB -> 4KB.
// B=64 S=256 V=50000 E=300 H=256 T=13
#define B_    64
#define S_    256
#define E_    300
#define H_    256
#define T_    13
#define G4_   1024   // 4*H
#define D2H_  512    // 2*H

typedef short bf16x8 __attribute__((ext_vector_type(8)));   // 8 bf16 in 4 VGPRs
typedef float f32x4  __attribute__((ext_vector_type(4)));
typedef unsigned short u16;
typedef unsigned long long u64;

__device__ __forceinline__ float sigf(float x)   { return __builtin_amdgcn_rcpf(1.f + __expf(-x)); }
__device__ __forceinline__ float tanhf_(float x) { return __builtin_amdgcn_rcpf(1.f + __expf(-2.f*x))*2.f - 1.f; }

__device__ __forceinline__ u16 f2bf(float f) {
  union { float f; unsigned u; } v; v.f = f;
  unsigned r = v.u + 0x7fff + ((v.u >> 16) & 1);   // RNE
  return (u16)(r >> 16);
}
__device__ __forceinline__ float bf2f(u16 h) {
  union { unsigned u; float f; } v; v.u = ((unsigned)h) << 16;
  return v.f;
}

// coherent (agent-scope, relaxed) accessors
__device__ __forceinline__ u64 cload64(const u64* p) {
  return __hip_atomic_load(p, __ATOMIC_RELAXED, __HIP_MEMORY_SCOPE_AGENT);
}
__device__ __forceinline__ void cstore32(unsigned* p, unsigned v) {
  __hip_atomic_store(p, v, __ATOMIC_RELAXED, __HIP_MEMORY_SCOPE_AGENT);
}

// ---------------- embedding gather -> bf16 hi/lo, K padded 300->320 ----------------
__global__ __launch_bounds__(64)
void k_embed(const int* __restrict__ x, const float* __restrict__ emb,
             u16* __restrict__ oh, u16* __restrict__ ol) {
  int bs = blockIdx.x;
  int xv = x[bs];
  const float4* src = (const float4*)(emb + (size_t)xv * E_);
  u64* dh = (u64*)(oh + (size_t)bs * 320);
  u64* dl = (u64*)(ol + (size_t)bs * 320);
  for (int q = threadIdx.x; q < 80; q += 64) {
    float4 v = (q < 75) ? src[q] : make_float4(0.f, 0.f, 0.f, 0.f);
    u16 hh[4], ll[4];
    float vv[4] = {v.x, v.y, v.z, v.w};
    #pragma unroll
    for (int j = 0; j < 4; j++) {
      hh[j] = f2bf(vv[j]);
      ll[j] = f2bf(vv[j] - bf2f(hh[j]));
    }
    dh[q] = (u64)hh[0] | ((u64)hh[1] << 16) | ((u64)hh[2] << 32) | ((u64)hh[3] << 48);
    dl[q] = (u64)ll[0] | ((u64)ll[1] << 16) | ((u64)ll[2] << 32) | ((u64)ll[3] << 48);
  }
}

// ---------------- fp32 -> bf16 hi/lo split (flat) ----------------
__global__ __launch_bounds__(256)
void k_cvtbf2(const float* __restrict__ w, u16* __restrict__ hi, u16* __restrict__ lo, int n) {
  int i = blockIdx.x * 256 + threadIdx.x;
  if (i < n) {
    float v = w[i];
    u16 h = f2bf(v);
    hi[i] = h;
    lo[i] = f2bf(v - bf2f(h));
  }
}

// ---------------- fp32 -> bf16 hi/lo with K padding (per-row) ----------------
__global__ __launch_bounds__(256)
void k_cvtpad(const float* __restrict__ w, u16* __restrict__ hi, u16* __restrict__ lo,
              int Ksrc, int Kpad) {
  int r = blockIdx.x;
  for (int k = threadIdx.x; k < Kpad; k += 256) {
    float v = (k < Ksrc) ? w[(size_t)r * Ksrc + k] : 0.f;
    u16 h = f2bf(v);
    hi[(size_t)r * Kpad + k] = h;
    lo[(size_t)r * Kpad + k] = f2bf(v - bf2f(h));
  }
}

// ---------------- cond_w (512,256) -> transposed hi/lo (256,512) ----------------
__global__ __launch_bounds__(256)
void k_cvtT(const float* __restrict__ w, u16* __restrict__ hi, u16* __restrict__ lo) {
  int n = blockIdx.x;
  for (int k = threadIdx.x; k < 512; k += 256) {
    float v = w[(size_t)k * 256 + n];
    u16 h = f2bf(v);
    hi[(size_t)n * 512 + k] = h;
    lo[(size_t)n * 512 + k] = f2bf(v - bf2f(h));
  }
}

// ---------------- split-bf16 MFMA GEMM: C = A @ W^T + bias (round-6) ----------------
__global__ __launch_bounds__(256)
void k_bgemm(const u16* __restrict__ Ahi, const u16* __restrict__ Alo,
             const u16* __restrict__ Whi, const u16* __restrict__ Wlo,
             const float* __restrict__ bias, float* __restrict__ C,
             int K, int N, int permute, long wStride, long bStride, long cStride)
{
  __shared__ u16 Ash[2][128 * 40];
  __shared__ u16 Wsh[2][128 * 40];

  int tid = threadIdx.x;
  int d   = blockIdx.z;
  int n0  = blockIdx.x * 128, m0 = blockIdx.y * 128;
  int lane = tid & 63;
  int w    = tid >> 6;
  int l15  = lane & 15;
  int quad = lane >> 4;
  int mh = (w >> 1) * 64, nh = (w & 1) * 64;

  int comp = tid >> 7, row = tid & 127;
  int gr = m0 + row;
  int ar = permute ? ((gr & 63) * S_ + (gr >> 6)) : gr;
  const u16* Asrc = (comp ? Alo : Ahi) + (size_t)ar * K;
  const u16* Wsrc = (comp ? Wlo : Whi) + (size_t)d * wStride + (size_t)(n0 + row) * K;
  u16* AshC = &Ash[comp][row * 40];
  u16* WshC = &Wsh[comp][row * 40];

  f32x4 acc[4][4];
  #pragma unroll
  for (int mt = 0; mt < 4; mt++)
    #pragma unroll
    for (int nt = 0; nt < 4; nt++) acc[mt][nt] = (f32x4)(0.f);

  for (int k0 = 0; k0 < K; k0 += 32) {
    float4 a0 = *(const float4*)(Asrc + k0);
    float4 a1 = *(const float4*)(Asrc + k0 + 8);
    float4 a2 = *(const float4*)(Asrc + k0 + 16);
    float4 a3 = *(const float4*)(Asrc + k0 + 24);
    float4 w0 = *(const float4*)(Wsrc + k0);
    float4 w1 = *(const float4*)(Wsrc + k0 + 8);
    float4 w2 = *(const float4*)(Wsrc + k0 + 16);
    float4 w3 = *(const float4*)(Wsrc + k0 + 24);
    __syncthreads();
    *(float4*)(AshC)      = a0; *(float4*)(AshC + 8)  = a1;
    *(float4*)(AshC + 16) = a2; *(float4*)(AshC + 24) = a3;
    *(float4*)(WshC)      = w0; *(float4*)(WshC + 8)  = w1;
    *(float4*)(WshC + 16) = w2; *(float4*)(WshC + 24) = w3;
    __syncthreads();

    bf16x8 ah[4], al[4], bh[4], bl[4];
    #pragma unroll
    for (int mt = 0; mt < 4; mt++) {
      int rr = mh + mt * 16 + l15;
      ah[mt] = *(const bf16x8*)&Ash[0][rr * 40 + quad * 8];
      al[mt] = *(const bf16x8*)&Ash[1][rr * 40 + quad * 8];
    }
    #pragma unroll
    for (int nt = 0; nt < 4; nt++) {
      int rr = nh + nt * 16 + l15;
      bh[nt] = *(const bf16x8*)&Wsh[0][rr * 40 + quad * 8];
      bl[nt] = *(const bf16x8*)&Wsh[1][rr * 40 + quad * 8];
    }
    #pragma unroll
    for (int mt = 0; mt < 4; mt++)
      #pragma unroll
      for (int nt = 0; nt < 4; nt++) {
        acc[mt][nt] = __builtin_amdgcn_mfma_f32_16x16x32_bf16(ah[mt], bh[nt], acc[mt][nt], 0, 0, 0);
        acc[mt][nt] = __builtin_amdgcn_mfma_f32_16x16x32_bf16(ah[mt], bl[nt], acc[mt][nt], 0, 0, 0);
        acc[mt][nt] = __builtin_amdgcn_mfma_f32_16x16x32_bf16(al[mt], bh[nt], acc[mt][nt], 0, 0, 0);
      }
  }

  const float* biasd = bias + (size_t)d * bStride;
  float* Cd = C + (size_t)d * cStride;
  #pragma unroll
  for (int nt = 0; nt < 4; nt++) {
    int cn = n0 + nh + nt * 16 + l15;
    float bv = biasd[cn];
    #pragma unroll
    for (int mt = 0; mt < 4; mt++) {
      int mr = m0 + mh + mt * 16 + quad * 4;
      #pragma unroll
      for (int j = 0; j < 4; j++)
        Cd[(size_t)(mr + j) * N + cn] = acc[mt][nt][j] + bv;
    }
  }
}

// ---------------- split-bf16 MFMA LSTM, 4-batch islands, r6 exchange ----------------
// 256 WGs: blockIdx.x = d*128 + bg*8 + us. Island = (d,bg): 8 slice-WGs, 4 batches.
// Exchange identical to round 6 (coherent u32 hi/lo stores, drain barrier, magic
// flag, consumer spins 8 flags then bulk-pulls once) — just 4KB/step instead of 16KB.
// hb_hi/hb_lo: [32 islands][S][4][256] bf16. flags: [32 islands][S][8].
__global__ __launch_bounds__(256, 1)
void k_lstm_mfma(const float* __restrict__ xg,
                 const u16* __restrict__ Whi, const u16* __restrict__ Wlo,
                 u16* __restrict__ houth, u16* __restrict__ houtl,
                 u16* __restrict__ hb_hi, u16* __restrict__ hb_lo,
                 unsigned* __restrict__ flags, unsigned magic)
{
  __shared__ __align__(16) u16   hsh[4 * 256];         // 2 KB hi slab
  __shared__ __align__(16) u16   hsl[4 * 256];         // 2 KB lo slab
  __shared__ __align__(16) float gl[4 * 16 * 34];      // gates [g][b-row][u32 pad34]

  int tid  = threadIdx.x;
  int us   = blockIdx.x & 7;
  int bg   = (blockIdx.x >> 3) & 15;
  int d    = blockIdx.x >> 7;
  int lane = tid & 63;
  int gate = tid >> 6;
  int l15  = lane & 15;
  int quad = lane >> 4;
  int bpc  = l15 & 3;                 // real batch column (cols 4-15 alias/discard)

  // A-frags: A[m=l15][k=quad*8+j]; row = gate*256 + us*32 + mt*16 + l15 (r6 layout)
  bf16x8 afh[2][8], afl[2][8];
  {
    const u16* WbH = Whi + ((size_t)d * G4_ + gate * 256 + us * 32 + l15) * H_;
    const u16* WbL = Wlo + ((size_t)d * G4_ + gate * 256 + us * 32 + l15) * H_;
    #pragma unroll
    for (int mt = 0; mt < 2; mt++)
      #pragma unroll
      for (int kt = 0; kt < 8; kt++) {
        afh[mt][kt] = *(const bf16x8*)(WbH + (size_t)mt * 16 * H_ + kt * 32 + quad * 8);
        afl[mt][kt] = *(const bf16x8*)(WbL + (size_t)mt * 16 * H_ + kt * 32 + quad * 8);
      }
  }

  float c0 = 0.f, c1 = 0.f;
  // staging: thread t loads 1 hi u64 + 1 lo u64 of the 4KB slab
  int sb = tid >> 6;                  // batch row 0..3
  int cw = tid & 63;                  // u64 chunk within row (4 units each)
  int sch = cw >> 1, shalf = cw & 1;  // 8-u16 chunk + half for XOR swizzle
  int scc = sch ^ sb;
  // cell: tid < 64: bc = batch, uo2 = unit pair base within slice
  int bc = tid & 3, uo2 = (tid >> 2) * 2;

  const float* xgd = xg + (size_t)d * S_ * B_ * G4_;
  size_t isl = (size_t)(d * 16 + bg) * S_ * 4 * 256;
  u16* hbh = hb_hi + isl;
  u16* hbl = hb_lo + isl;
  unsigned* fl = flags + (d * 16 + bg) * S_ * 8;

  for (int it = 0; it < S_; it++) {
    int s = d ? (S_ - 1 - it) : it;

    // acc init from xg (cols 4-15 alias batch l15&3 — discarded later)
    f32x4 acc[2];
    const float* xgrow = xgd + (size_t)s * B_ * G4_ + (size_t)(bg * 4 + bpc) * G4_
                       + gate * 256 + us * 32;
    acc[0] = *(const f32x4*)(xgrow + quad * 4);
    acc[1] = *(const f32x4*)(xgrow + 16 + quad * 4);

    if (it > 0) {
      // wait for all 8 slices of previous step's h (this island)
      if (tid < 8) {
        const unsigned* f = &fl[(it - 1) * 8 + tid];
        while (__hip_atomic_load(f, __ATOMIC_RELAXED, __HIP_MEMORY_SCOPE_AGENT) != magic)
          __builtin_amdgcn_s_sleep(1);
      }
      __syncthreads();

      // bulk pull 4KB slab (hi+lo) -> LDS, XOR chunk swizzle: 1 u64 each per comp
      {
        u64 th = cload64((const u64*)(hbh + (size_t)(it - 1) * 1024) + tid);
        u64 tl = cload64((const u64*)(hbl + (size_t)(it - 1) * 1024) + tid);
        *(u64*)&hsh[sb * 256 + scc * 8 + shalf * 4] = th;
        *(u64*)&hsl[sb * 256 + scc * 8 + shalf * 4] = tl;
      }
      __syncthreads();

      #pragma unroll
      for (int kt = 0; kt < 8; kt++) {
        int cc = (kt * 4 + quad) ^ bpc;
        bf16x8 bh = *(const bf16x8*)&hsh[bpc * 256 + cc * 8];
        bf16x8 bl = *(const bf16x8*)&hsl[bpc * 256 + cc * 8];
        #pragma unroll
        for (int mt = 0; mt < 2; mt++) {
          acc[mt] = __builtin_amdgcn_mfma_f32_16x16x32_bf16(afh[mt][kt], bh, acc[mt], 0, 0, 0);
          acc[mt] = __builtin_amdgcn_mfma_f32_16x16x32_bf16(afh[mt][kt], bl, acc[mt], 0, 0, 0);
          acc[mt] = __builtin_amdgcn_mfma_f32_16x16x32_bf16(afl[mt][kt], bh, acc[mt], 0, 0, 0);
        }
      }
    }

    // publish gates: u_local = mt*16 + quad*4 + r, batch-row = l15 (rows >=4 unused)
    #pragma unroll
    for (int mt = 0; mt < 2; mt++)
      *(f32x4*)&gl[(gate * 16 + l15) * 34 + mt * 16 + quad * 4] = acc[mt];
    __syncthreads();

    if (tid < 64) {
      // cell update: thread owns (bc, units uo2, uo2+1)
      float2 vi = *(const float2*)&gl[(0 * 16 + bc) * 34 + uo2];
      float2 vf = *(const float2*)&gl[(1 * 16 + bc) * 34 + uo2];
      float2 vg = *(const float2*)&gl[(2 * 16 + bc) * 34 + uo2];
      float2 vo = *(const float2*)&gl[(3 * 16 + bc) * 34 + uo2];
      c0 = sigf(vf.x) * c0 + sigf(vi.x) * tanhf_(vg.x);
      c1 = sigf(vf.y) * c1 + sigf(vi.y) * tanhf_(vg.y);
      float h0 = sigf(vo.x) * tanhf_(c0);
      float h1 = sigf(vo.y) * tanhf_(c1);

      u16 h0h = f2bf(h0), h1h = f2bf(h1);
      u16 h0l = f2bf(h0 - bf2f(h0h)), h1l = f2bf(h1 - bf2f(h1h));
      unsigned phv = (unsigned)h0h | ((unsigned)h1h << 16);
      unsigned plv = (unsigned)h0l | ((unsigned)h1l << 16);

      // h -> layer output (bf16 hi/lo, plain stores)
      size_t ho = ((size_t)(bg * 4 + bc) * S_ + s) * D2H_ + d * H_ + us * 32 + uo2;
      *(unsigned*)(houth + ho) = phv;
      *(unsigned*)(houtl + ho) = plv;

      // h -> exchange buffers (agent-coherent)
      size_t hoff = (size_t)it * 1024 + bc * 256 + us * 32 + uo2;
      cstore32((unsigned*)(hbh + hoff), phv);
      cstore32((unsigned*)(hbl + hoff), plv);
    }

    __syncthreads();   // drains producing threads' coherent stores + protects gl/hs reuse
    if (tid == 0)
      __hip_atomic_store(&fl[it * 8 + us], magic, __ATOMIC_RELAXED, __HIP_MEMORY_SCOPE_AGENT);
  }
}

// ---------------- block reduction helpers ----------------
__device__ __forceinline__ float bsum(float v, float* sb) {
  int t = threadIdx.x;
  sb[t] = v; __syncthreads();
  for (int s = 128; s; s >>= 1) { if (t < s) sb[t] += sb[t + s]; __syncthreads(); }
  float r = sb[0]; __syncthreads(); return r;
}
__device__ __forceinline__ float bmax(float v, float* sb) {
  int t = threadIdx.x;
  sb[t] = v; __syncthreads();
  for (int s = 128; s; s >>= 1) { if (t < s) sb[t] = fmaxf(sb[t], sb[t + s]); __syncthreads(); }
  float r = sb[0]; __syncthreads(); return r;
}

// ---------------- pos branch ----------------
__global__ __launch_bounds__(256)
void k_pos(const float* __restrict__ pos, const float* __restrict__ fc1w, const float* __restrict__ fc1b,
           const float* __restrict__ fc2w, const float* __restrict__ fc2b,
           const float* __restrict__ lng, const float* __restrict__ lnb, float* __restrict__ pos_out)
{
  __shared__ float sp[256], sh[256], sb[256];
  int b = blockIdx.x, t = threadIdx.x;
  sp[t] = pos[b * 256 + t];
  __syncthreads();
  float a1 = fc1b[t];
  for (int s = 0; s < 256; s++) a1 += sp[s] * fc1w[s * 256 + t];
  a1 = fmaxf(a1, 0.f);
  sh[t] = a1; __syncthreads();
  float a2 = fc2b[t] + sp[t];
  for (int s = 0; s < 256; s++) a2 += sh[s] * fc2w[s * 256 + t];
  float m   = bsum(a2, sb) * (1.f / 256.f);
  float cen = a2 - m;
  float var = bsum(cen * cen, sb) * (1.f / 256.f);
  pos_out[b * 256 + t] = cen * rsqrtf(var + 1e-5f) * lng[t] + lnb[t];
}

// ---------------- CLN stage A ----------------
__global__ __launch_bounds__(256)
void k_clnA(const float* __restrict__ pos_out, const float* __restrict__ wd, const float* __restrict__ bd,
            const float* __restrict__ cw, const float* __restrict__ cb,
            float* __restrict__ wvec, float* __restrict__ bbvec)
{
  __shared__ float sp[256];
  int b = blockIdx.x, t = threadIdx.x;
  sp[t] = pos_out[b * 256 + t];
  __syncthreads();
  const float4* wdr = (const float4*)(wd + (size_t)t * 256);
  const float4* bdr = (const float4*)(bd + (size_t)t * 256);
  float aw = 0.f, ab = 0.f;
  for (int q = 0; q < 64; q++) {
    float4 w4 = wdr[q], b4 = bdr[q];
    float s0 = sp[q*4], s1 = sp[q*4+1], s2 = sp[q*4+2], s3 = sp[q*4+3];
    aw += s0*w4.x + s1*w4.y + s2*w4.z + s3*w4.w;
    ab += s0*b4.x + s1*b4.y + s2*b4.z + s3*b4.w;
  }
  wvec [b * 256 + t] = aw + cw[t];
  bbvec[b * 256 + t] = ab + cb[t];
}

// ---------------- CLN stage B + sentence dot ----------------
__global__ __launch_bounds__(256)
void k_clnB(const float* __restrict__ oc, const float* __restrict__ wvec, const float* __restrict__ bbvec,
            const float* __restrict__ alw, const float* __restrict__ alb,
            float* __restrict__ outn, float* __restrict__ sentence)
{
  __shared__ float sb[256];
  int bs = blockIdx.x, t = threadIdx.x;
  int b = bs >> 8;
  float v   = oc[(size_t)bs * 256 + t];
  float m   = bsum(v, sb) * (1.f / 256.f);
  float cen = v - m;
  float var = bsum(cen * cen, sb) * (1.f / 256.f);
  float o   = cen * rsqrtf(var + 1e-12f) * wvec[b * 256 + t] + bbvec[b * 256 + t];
  outn[(size_t)bs * 256 + t] = o;
  float sv = bsum(o * alw[t], sb);
  if (t == 0) sentence[bs] = sv + alb[0];
}

// ---------------- attention ----------------
__global__ __launch_bounds__(256)
void k_att(const float* __restrict__ sentence,
           const float* __restrict__ wq, const float* __restrict__ bq,
           const float* __restrict__ wk, const float* __restrict__ bk,
           const float* __restrict__ wv, const float* __restrict__ bv,
           const float* __restrict__ lng, const float* __restrict__ lnb,
           float* __restrict__ att)
{
  __shared__ float ss[256], sb[256];
  int b = blockIdx.x, t = threadIdx.x;
  ss[t] = sentence[b * 256 + t];
  __syncthreads();
  float q = bq[t], k = bk[t], vv = bv[t];
  for (int s = 0; s < 256; s++) {
    float sv = ss[s];
    q  += sv * wq[s * 256 + t];
    k  += sv * wk[s * 256 + t];
    vv += sv * wv[s * 256 + t];
  }
  float x  = q * k * (1.f / 16.f);
  float mx = bmax(x, sb);
  float e  = expf(x - mx);
  float sm = bsum(e, sb);
  float a  = (e / sm) * vv;
  float m   = bsum(a, sb) * (1.f / 256.f);
  float cen = a - m;
  float var = bsum(cen * cen, sb) * (1.f / 256.f);
  att[b * 256 + t] = cen * rsqrtf(var + 1e-5f) * lng[t] + lnb[t];
}

// ---------------- logits ----------------
__global__ __launch_bounds__(64)
void k_out(const float* __restrict__ outn, const float* __restrict__ att,
           const float* __restrict__ ow, const float* __restrict__ ob,
           float* __restrict__ logits)
{
  __shared__ float row[256];
  int bs = blockIdx.x, t = threadIdx.x;
  ((float4*)row)[t] = ((const float4*)(outn + (size_t)bs * 256))[t];
  __syncthreads();
  float a = att[bs];
  if (t < T_) {
    float acc = 0.f;
    for (int c = 0; c < 256; c++) acc += row[c] * ow[c * T_ + t];
    logits[(size_t)bs * T_ + t] = a * acc + ob[t];
  }
}

// ---------------- Viterbi ----------------
__global__ __launch_bounds__(64)
void k_viterbi(const float* __restrict__ logits, const float* __restrict__ start,
               const float* __restrict__ endv, const float* __restrict__ trans,
               float* __restrict__ tags)
{
  __shared__ float sc[16];
  __shared__ float str[169];
  __shared__ unsigned char hist[255 * 13];
  __shared__ int tg[256];
  int b = blockIdx.x, t = threadIdx.x;
  for (int i = t; i < 169; i += 64) str[i] = trans[i];
  if (t < 13) sc[t] = start[t] + logits[((size_t)b * 256) * 13 + t];
  __syncthreads();
  for (int s = 1; s < 256; s++) {
    float best = -1e30f; int bi = 0;
    if (t < 13) {
      best = sc[0] + str[t]; bi = 0;
      for (int i = 1; i < 13; i++) {
        float v = sc[i] + str[i * 13 + t];
        if (v > best) { best = v; bi = i; }
      }
    }
    __syncthreads();
    if (t < 13) {
      sc[t] = best + logits[((size_t)b * 256 + s) * 13 + t];
      hist[(s - 1) * 13 + t] = (unsigned char)bi;
    }
    __syncthreads();
  }
  if (t == 0) {
    float best = sc[0] + endv[0]; int last = 0;
    for (int j = 1; j < 13; j++) {
      float v = sc[j] + endv[j];
      if (v > best) { best = v; last = j; }
    }
    tg[255] = last;
    int cur = last;
    for (int s = 254; s >= 0; s--) { cur = hist[s * 13 + cur]; tg[s] = cur; }
  }
  __syncthreads();
  for (int s = t; s < 256; s += 64) tags[b * 256 + s] = (float)tg[s];
}

// ---------------- launch ----------------
extern "C" void kernel_launch(void* const* d_in, const int* in_sizes, int n_in,
                              void* d_out, int out_size, void* d_ws, size_t ws_size,
                              hipStream_t stream)
{
  const int*   x     = (const int*)  d_in[0];
  const float* pos   = (const float*)d_in[1];
  const float* emb   = (const float*)d_in[2];
  const float* Wih0  = (const float*)d_in[3];
  const float* Whh0  = (const float*)d_in[4];
  const float* b0    = (const float*)d_in[5];
  const float* Wih1  = (const float*)d_in[6];
  const float* Whh1  = (const float*)d_in[7];
  const float* b1    = (const float*)d_in[8];
  const float* fc1w  = (const float*)d_in[9];
  const float* fc1b  = (const float*)d_in[10];
  const float* fc2w  = (const float*)d_in[11];
  const float* fc2b  = (const float*)d_in[12];
  const float* plng  = (const float*)d_in[13];
  const float* plnb  = (const float*)d_in[14];
  const float* condw = (const float*)d_in[15];
  const float* condb = (const float*)d_in[16];
  const float* clnw  = (const float*)d_in[17];
  const float* clnb  = (const float*)d_in[18];
  const float* clnwd = (const float*)d_in[19];
  const float* clnbd = (const float*)d_in[20];
  const float* wq    = (const float*)d_in[21];
  const float* bq    = (const float*)d_in[22];
  const float* wk    = (const float*)d_in[23];
  const float* bk    = (const float*)d_in[24];
  const float* wv    = (const float*)d_in[25];
  const float* bv    = (const float*)d_in[26];
  const float* atlng = (const float*)d_in[27];
  const float* atlnb = (const float*)d_in[28];
  const float* alw   = (const float*)d_in[29];
  const float* alb   = (const float*)d_in[30];
  const float* ow    = (const float*)d_in[31];
  const float* ob    = (const float*)d_in[32];
  const float* cstart= (const float*)d_in[33];
  const float* cend  = (const float*)d_in[34];
  const float* ctrans= (const float*)d_in[35];

  const size_t BS = (size_t)B_ * S_;   // 16384
  float* ws = (float*)d_ws;
  float* r1   = ws;                    // embA hi/lo -> out_cond
  float* xg   = r1 + 5242880;          // fp32 pre-gates [2][S][B][1024]
  float* l0r  = xg + 33554432;         // l0 hi/lo -> lstm1 exchange -> outn
  float* l1r  = l0r + 8388608;         // lstm0 exchange -> l1 hi/lo
  float* pos_out  = l1r + 8388608;
  float* wvec     = pos_out + 16384;
  float* bbvec    = wvec + 16384;
  float* sentence = bbvec + 16384;
  float* attv     = sentence + 16384;
  unsigned* flags = (unsigned*)(attv + 16384);     // 2*16*256*8 = 65536 u32
  u16* whhh0 = (u16*)(flags + 65536);              // Whh splits: 4 x 524288 u16
  u16* whhl0 = whhh0 + 524288;
  u16* whhh1 = whhl0 + 524288;
  u16* whhl1 = whhh1 + 524288;
  u16* wih0h = whhl1 + 524288;                     // [2][1024][320]
  u16* wih0l = wih0h + 655360;
  u16* wih1h = wih0l + 655360;                     // [2][1024][512]
  u16* wih1l = wih1h + 1048576;
  u16* condTh = wih1l + 1048576;                   // [256][512]
  u16* condTl = condTh + 131072;

  u16* embh = (u16*)r1;
  u16* embl = embh + 5242880;
  float* out_cond = r1;
  u16* l0h = (u16*)l0r;
  u16* l0l = l0h + 8388608;
  u16* l1h = (u16*)l1r;
  u16* l1l = l1h + 8388608;
  const size_t HBN = (size_t)32 * S_ * 4 * 256;    // 8,388,608 u16 per component
  u16* hb0 = (u16*)l1r;                 // lstm0 exchange (l1r free until lstm1 hout)
  u16* hb1 = (u16*)l0r;                 // lstm1 exchange (l0 consumed by bgemm1)
  float* outn = l0r;
  float* logits = (float*)d_out;
  float* tags   = logits + BS * T_;

  k_embed <<<dim3(B_ * S_), dim3(64), 0, stream>>>(x, emb, embh, embl);
  k_cvtbf2<<<dim3(2048), dim3(256), 0, stream>>>(Whh0, whhh0, whhl0, 2 * G4_ * H_);
  k_cvtbf2<<<dim3(2048), dim3(256), 0, stream>>>(Whh1, whhh1, whhl1, 2 * G4_ * H_);
  k_cvtpad<<<dim3(2048), dim3(256), 0, stream>>>(Wih0, wih0h, wih0l, 300, 320);
  k_cvtpad<<<dim3(2048), dim3(256), 0, stream>>>(Wih1, wih1h, wih1l, 512, 512);
  k_cvtT  <<<dim3(256),  dim3(256), 0, stream>>>(condw, condTh, condTl);

  // layer-0 pre-gates (split-bf16 MFMA)
  k_bgemm<<<dim3(8, 128, 2), dim3(256), 0, stream>>>(
      embh, embl, wih0h, wih0l, b0, xg, 320, G4_, 1,
      (long)G4_ * 320, (long)G4_, (long)BS * G4_);
  k_lstm_mfma<<<dim3(256), dim3(256), 0, stream>>>(
      xg, whhh0, whhl0, l0h, l0l, hb0, hb0 + HBN, flags, 0x51A75A01u);

  // layer-1 pre-gates
  k_bgemm<<<dim3(8, 128, 2), dim3(256), 0, stream>>>(
      l0h, l0l, wih1h, wih1l, b1, xg, 512, G4_, 1,
      (long)G4_ * 512, (long)G4_, (long)BS * G4_);
  k_lstm_mfma<<<dim3(256), dim3(256), 0, stream>>>(
      xg, whhh1, whhl1, l1h, l1l, hb1, hb1 + HBN, flags, 0x51A75A02u);

  // cond projection
  k_bgemm<<<dim3(2, 128, 1), dim3(256), 0, stream>>>(
      l1h, l1l, condTh, condTl, condb, out_cond, 512, 256, 0, 0, 0, 0);

  k_pos <<<dim3(B_), dim3(256), 0, stream>>>(pos, fc1w, fc1b, fc2w, fc2b, plng, plnb, pos_out);
  k_clnA<<<dim3(B_), dim3(256), 0, stream>>>(pos_out, clnwd, clnbd, clnw, clnb, wvec, bbvec);
  k_clnB<<<dim3(B_ * S_), dim3(256), 0, stream>>>(out_cond, wvec, bbvec, alw, alb, outn, sentence);
  k_att <<<dim3(B_), dim3(256), 0, stream>>>(sentence, wq, bq, wk, bk, wv, bv, atlng, atlnb, attv);
  k_out <<<dim3(B_ * S_), dim3(64), 0, stream>>>(outn, attv, ow, ob, logits);
  k_viterbi<<<dim3(B_), dim3(64), 0, stream>>>(logits, cstart, cend, ctrans, tags);
}